// Round 1
// 677.337 us; speedup vs baseline: 1.3497x; 1.3497x over previous
//
#include <hip/hip_runtime.h>

// CTRNN forward, B=256 T=2048 D=32 H=64. ALL tensors fp32.
// r4: two changes vs the 914us kernel:
//  (A) xproj: x-row broadcast loads (16B/instr, latency-bound, ~0.6 TB/s)
//      replaced by coalesced float4 staging of the 32KB x-tile into LDS;
//      broadcast reads now come from LDS. Target ~memory roofline.
//  (B) recur: the per-step LDS round trip (ds_write hs -> ds_read, ~300+cyc
//      on the serial chain at 1 wave/CU) replaced by v_readlane broadcasts:
//      h[k] lives in lane k's register; readlane -> SGPR -> FMA operand.
//      No LDS, no barriers, chain is pure VALU issue (~100 instr/step).
// Accumulation order kept bit-identical to the 914us version (absmax 0.0078).

#define Bb 256
#define Tt 2048
#define Dd 32
#define Hh 64

typedef float v2f __attribute__((ext_vector_type(2)));

static constexpr float ALPHA = (float)(16.67 / 40.0);
static constexpr float OMA   = 1.0f - ALPHA;

static __device__ inline v2f vfma2(v2f a, v2f b, v2f c) {
#if __has_builtin(__builtin_elementwise_fma)
    return __builtin_elementwise_fma(a, b, c);
#else
    v2f r; r.x = fmaf(a.x, b.x, c.x); r.y = fmaf(a.y, b.y, c.y); return r;
#endif
}

// ---------------- Phase A: out[b][t][h] = dot(x[b][t][:], W_in[h][:]) -------
// grid 2048 = 256 b x 8 tiles, block 256 (4 waves). 32KB x-tile staged into
// LDS with coalesced float4 loads (1KB/instr); per-step row reads are LDS
// broadcasts (same addr all lanes -> conflict-free). Stores coalesced.
__global__ __launch_bounds__(256) void ctrnn_xproj(
    const float* __restrict__ x,
    const float* __restrict__ W_in,
    float* __restrict__ out)
{
    __shared__ alignas(16) float xs[256 * Dd];   // 32 KB
    const int tid  = threadIdx.x;
    const int lane = tid & 63;
    const int wave = tid >> 6;
    const int b    = blockIdx.x >> 3;
    const int tile = blockIdx.x & 7;
    const int t0   = tile * 256;

    // coalesced stage: 8192 floats = 2048 float4 = 8 rounds x 256 threads
    const float4* xsrc = reinterpret_cast<const float4*>(
        x + (size_t)b * Tt * Dd + (size_t)t0 * Dd);
    float4* xdst = reinterpret_cast<float4*>(xs);
#pragma unroll
    for (int r = 0; r < 8; ++r) xdst[r * 256 + tid] = xsrc[r * 256 + tid];

    float4 w[8];
    const float4* wrow = reinterpret_cast<const float4*>(W_in + lane * Dd);
#pragma unroll
    for (int j = 0; j < 8; ++j) w[j] = wrow[j];

    __syncthreads();

    float* ob = out + (size_t)b * Tt * Hh;
    const int lt0 = wave * 64;
    for (int i = 0; i < 64; ++i) {
        const float4* xr = reinterpret_cast<const float4*>(xs + (lt0 + i) * Dd);
        float s0 = 0.f, s1 = 0.f, s2 = 0.f, s3 = 0.f;
#pragma unroll
        for (int j = 0; j < 8; ++j) {
            const float4 xv = xr[j];
            s0 = fmaf(w[j].x, xv.x, s0);
            s1 = fmaf(w[j].y, xv.y, s1);
            s2 = fmaf(w[j].z, xv.z, s2);
            s3 = fmaf(w[j].w, xv.w, s3);
        }
        ob[(size_t)(t0 + lt0 + i) * Hh + lane] = (s0 + s1) + (s2 + s3);
    }
}

// ---------------- Phase B: sequential recurrence, 1 wave per batch ----------
// h state: lane k holds h[k] in a register ("hold"). Broadcast via
// v_readlane (register->SGPR), no LDS anywhere. xp read from out rows
// (written by phase A), 8-deep register ring prefetch; row t is overwritten
// with h_t after its xp is consumed (same-lane, constant-offset disjoint).
__global__ __launch_bounds__(64) void ctrnn_recur(
    const float* __restrict__ b_in,
    const float* __restrict__ W_hh,
    const float* __restrict__ b_hh,
    float* __restrict__ out)
{
    const int b    = blockIdx.x;
    const int lane = threadIdx.x;

    v2f w[Hh / 2];
    const v2f* wrow = reinterpret_cast<const v2f*>(W_hh + lane * Hh);
#pragma unroll
    for (int j = 0; j < Hh / 2; ++j) w[j] = wrow[j];
    const float cb = ALPHA * (b_in[lane] + b_hh[lane]);

    float* ob = out + (size_t)b * Tt * Hh + lane;

    float xp[8];
#pragma unroll
    for (int j = 0; j < 8; ++j) xp[j] = ob[(size_t)j * Hh];

    float* op       = ob;                 // store ptr (row t)
    const float* lp = ob + 8 * (size_t)Hh; // refill ptr (row t+8)

    float hold = 0.0f;
    for (int t = 0; t < Tt; t += 8) {
#pragma unroll
        for (int j = 0; j < 8; ++j) {
            // broadcast h[k] from lane k via readlane; identical accumulation
            // order to the LDS version: acc0 <- cols 4k,4k+1; acc1 <- 4k+2,4k+3
            const int hb = __float_as_int(hold);
            v2f acc0 = {0.f, 0.f}, acc1 = {0.f, 0.f};
#pragma unroll
            for (int k = 0; k < 16; ++k) {
                v2f h01, h23;
                h01.x = __int_as_float(__builtin_amdgcn_readlane(hb, 4 * k + 0));
                h01.y = __int_as_float(__builtin_amdgcn_readlane(hb, 4 * k + 1));
                h23.x = __int_as_float(__builtin_amdgcn_readlane(hb, 4 * k + 2));
                h23.y = __int_as_float(__builtin_amdgcn_readlane(hb, 4 * k + 3));
                acc0 = vfma2(w[2 * k + 0], h01, acc0);
                acc1 = vfma2(w[2 * k + 1], h23, acc1);
            }
            const v2f accs  = acc0 + acc1;
            const float sum = (accs.x + accs.y) + xp[j];
            const float hnew = fmaxf(fmaf(ALPHA, sum, fmaf(OMA, hold, cb)), 0.0f);

            *op = hnew;                    // overwrite xp row t+j with h
            op += Hh;
            hold = hnew;

            // refill ring 8 ahead (in-bounds past Tt: lands in hlast region,
            // value never consumed)
            xp[j] = *lp;
            lp += Hh;
        }
    }
    // h_last
    out[(size_t)Bb * Tt * Hh + (size_t)b * Hh + lane] = hold;
}

extern "C" void kernel_launch(void* const* d_in, const int* in_sizes, int n_in,
                              void* d_out, int out_size, void* d_ws, size_t ws_size,
                              hipStream_t stream) {
    const float* x    = (const float*)d_in[0];
    // d_in[1] = seq_lengths (int32): forward value is mask-independent.
    const float* W_in = (const float*)d_in[2];
    const float* b_in = (const float*)d_in[3];
    const float* W_hh = (const float*)d_in[4];
    const float* b_hh = (const float*)d_in[5];
    float* out = (float*)d_out;

    ctrnn_xproj<<<dim3(Bb * 8), dim3(256), 0, stream>>>(x, W_in, out);
    ctrnn_recur<<<dim3(Bb), dim3(64), 0, stream>>>(b_in, W_hh, b_hh, out);
}